// Round 13
// baseline (386.535 us; speedup 1.0000x reference)
//
#include <hip/hip_runtime.h>
#include <hip/hip_bf16.h>

#define BB 2048
#define TT 128
#define NN (BB*TT)          // 262144
#define NVAL NN

// workspace layout (float offsets)
#define OFF_BCA   768u        // 96 combined air input bias
#define OFF_BCM   1632u       // 96 combined m input bias
#define OFF_W0P   2048u       // W0 B-frag pack (16384 bf16)
#define OFF_W1P   10240u      // W1 B-frag pack (65536 bf16)
#define OFF_WQKV  43008u      // attn_in_w B-frag pack
#define OFF_WO    44544u      // attn_out_w B-frag pack
#define OFF_WH2A  45568u      // air Whh fp16-pair pack: 96*16 uints
#define OFF_WH2M  47104u      // m Whh fp16-pair pack
#define OFF_WC2A  48640u      // air combined Wih fp16-pair pack: 96*4 uints
#define OFF_WC2M  49024u      // m combined Wih fp16-pair pack
#define OFF_AIRF  83968u      // air_feat bf16: NN*32 shorts = 4194304 floats
#define OFF_MF    4278272u    // m_feat bf16: 2*NN*32 shorts = 8388608 floats
#define OFF_MASK  12666880u   // N*2 mask floats

typedef __attribute__((ext_vector_type(8))) short short8;
typedef __attribute__((ext_vector_type(4))) float f32x4;
typedef _Float16 h2 __attribute__((ext_vector_type(2)));

__device__ __forceinline__ unsigned short f2bf(float f) {
    unsigned u = __builtin_bit_cast(unsigned, f);
    u += 0x7FFFu + ((u >> 16) & 1u);       // RNE
    return (unsigned short)(u >> 16);
}
__device__ __forceinline__ unsigned f2h(float f) {
    _Float16 h = (_Float16)f;
    return (unsigned)__builtin_bit_cast(unsigned short, h);
}
__device__ __forceinline__ unsigned pkh2(float a, float b) {
    return (f2h(b) << 16) | f2h(a);
}
__device__ __forceinline__ float dot2(unsigned w, unsigned x, float acc) {
    return __builtin_amdgcn_fdot2(__builtin_bit_cast(h2, w),
                                  __builtin_bit_cast(h2, x), acc, false);
}
__device__ __forceinline__ float fast_rcp(float x) {
    return __builtin_amdgcn_rcpf(x);
}

// ---------------- prep -----------------------------------------------------
__global__ __launch_bounds__(256) void prep_kernel(
    const float* __restrict__ enc_air_W, const float* __restrict__ enc_air_b,
    const float* __restrict__ enc_m_W,   const float* __restrict__ enc_m_b,
    const float* __restrict__ air_Wih,   const float* __restrict__ air_bih,
    const float* __restrict__ m_Wih,     const float* __restrict__ m_bih,
    const float* __restrict__ air_Whh,   const float* __restrict__ m_Whh,
    const float* __restrict__ W0,        const float* __restrict__ W1,
    const float* __restrict__ attn_in_w, const float* __restrict__ attn_out_w,
    float* __restrict__ ws)
{
    int b = blockIdx.x, t = threadIdx.x;
    if (b == 0) {
        if (t < 96) {
            float bacc = air_bih[t];
            for (int k = 0; k < 32; k++) bacc += air_Wih[t*32+k] * enc_air_b[k];
            ws[OFF_BCA + t] = bacc;
            float bacc2 = m_bih[t];
            for (int k = 0; k < 32; k++) bacc2 += m_Wih[t*32+k] * enc_m_b[k];
            ws[OFF_BCM + t] = bacc2;
        }
    } else if (b <= 32) {
        unsigned short* w1p = (unsigned short*)(ws + OFF_W1P);
        int base = ((b-1)*256 + t);
        int lane = base & 63;
        int ctf  = base >> 6;
        int ct   = ctf & 15, s = ctf >> 4;   // s 0..7
        int col = lane & 15, quad = lane >> 4;
        int k0 = s*32 + quad*8;
        int o  = ct*16 + col;
        #pragma unroll
        for (int j = 0; j < 8; j++)
            w1p[base*8 + j] = f2bf(W1[o*256 + k0 + j]);
    } else if (b <= 40) {
        unsigned short* w0p = (unsigned short*)(ws + OFF_W0P);
        int base = ((b-33)*256 + t);
        int lane = base & 63;
        int ctf  = base >> 6;
        int ct   = ctf & 15, s = ctf >> 4;   // s 0..1
        int col = lane & 15, quad = lane >> 4;
        int k0 = s*32 + quad*8;
        int o  = ct*16 + col;
        #pragma unroll
        for (int j = 0; j < 8; j++)
            w0p[base*8 + j] = f2bf(W0[o*64 + k0 + j]);
    } else if (b == 41) { // attention weight packs
        unsigned short* wqkv = (unsigned short*)(ws + OFF_WQKV);
        unsigned short* wop  = (unsigned short*)(ws + OFF_WO);
        for (int slot = t; slot < 512; slot += 256) {
            if (slot < 384) {
                int ct = slot >> 6, lane = slot & 63;
                int col = lane & 15, quad = lane >> 4;
                int o = ct*16 + col;
                #pragma unroll
                for (int j = 0; j < 8; j++)
                    wqkv[slot*8 + j] = f2bf(attn_in_w[o*32 + quad*8 + j]);
            } else {
                int s2 = slot - 384;
                int ct = s2 >> 6, lane = s2 & 63;
                int col = lane & 15, quad = lane >> 4;
                #pragma unroll
                for (int j = 0; j < 8; j++)
                    wop[s2*8 + j] = f2bf(attn_out_w[(ct*16+col)*32 + quad*8 + j]);
            }
        }
    } else if (b == 42) { // GRU Whh fp16-pair packs: [gate*32+o][16 pairs]
        unsigned* wa = (unsigned*)(ws + OFF_WH2A);
        unsigned* wm = (unsigned*)(ws + OFF_WH2M);
        for (int s = t; s < 3072; s += 256) {
            int s2 = (s < 1536) ? s : s - 1536;
            const float* W = (s < 1536) ? air_Whh : m_Whh;
            unsigned* dst = (s < 1536) ? wa : wm;
            int o = s2 >> 4, j = s2 & 15;
            dst[s2] = pkh2(W[o*32 + 2*j], W[o*32 + 2*j + 1]);
        }
    } else { // b == 43: combined input-weight fp16-pair packs: [gate*32+o][4 pairs]
        unsigned* wa = (unsigned*)(ws + OFF_WC2A);
        unsigned* wm = (unsigned*)(ws + OFF_WC2M);
        for (int s = t; s < 768; s += 256) {
            int s2 = (s < 384) ? s : s - 384;
            bool is_air = (s < 384);
            unsigned* dst = is_air ? wa : wm;
            int o = s2 >> 2, j = s2 & 3;
            int ni  = is_air ? 7 : 4;
            float c0 = 0.f, c1 = 0.f;
            int i0 = 2*j, i1 = 2*j + 1;
            if (i0 < ni)
                for (int k = 0; k < 32; k++)
                    c0 += (is_air ? air_Wih[o*32+k]*enc_air_W[k*7+i0]
                                  : m_Wih[o*32+k]*enc_m_W[k*4+i0]);
            if (i1 < ni)
                for (int k = 0; k < 32; k++)
                    c1 += (is_air ? air_Wih[o*32+k]*enc_air_W[k*7+i1]
                                  : m_Wih[o*32+k]*enc_m_W[k*4+i1]);
            dst[s2] = pkh2(c0, c1);
        }
    }
}

// ---------------- GRU (VALU + fp16 dot2, single row / 32-lane group) --------
// R10 structure (best measured). bf16 pair-dword feat stores; raw rcp in
// sigmoid/tanh (saves ~6 inst per divide vs refined division).
template<int NI, int NP, bool DO_MASK>
__device__ void gru_row(const float* __restrict__ in_base,
                        const unsigned* __restrict__ wc2,   // [3*32][4]
                        const float* __restrict__ bc,
                        const unsigned* __restrict__ wh2,   // [3*32][16]
                        const float* __restrict__ bhh,
                        float h0,
                        unsigned short* __restrict__ feat_out,
                        float* __restrict__ hT_out,
                        float* __restrict__ mask_out,
                        int lane, int half)
{
    unsigned whr[16], whz[16], whn[16];
    #pragma unroll
    for (int j = 0; j < 16; j++) {
        whr[j] = wh2[lane*16 + j];
        whz[j] = wh2[(32+lane)*16 + j];
        whn[j] = wh2[(64+lane)*16 + j];
    }
    unsigned cr2[NP], cz2[NP], cn2[NP];
    #pragma unroll
    for (int j = 0; j < NP; j++) {
        cr2[j] = wc2[lane*4 + j];
        cz2[j] = wc2[(32+lane)*4 + j];
        cn2[j] = wc2[(64+lane)*4 + j];
    }
    const float bcr = bc[lane], bcz = bc[32+lane], bcn = bc[64+lane];
    const float bhr = bhh[lane], bhz = bhh[32+lane], bhn = bhh[64+lane];

    float h = h0;
    for (int t = 0; t < TT; t++) {
        float xin = (lane < NI) ? in_base[t*15 + lane] : 0.f;

        bool ok = true;
        if (DO_MASK) {
            bool pred = true;
            if (lane < 4) {
                const float c   = ((lane & 1) == 0) ? 1.f : 0.f;
                const float thr = ((lane & 1) == 0) ? 1.00001e-5f : 1e-8f;
                pred = fabsf(xin - c) <= thr;
            }
            unsigned long long ball = __ballot(pred);
            ok = (((ball >> (half*32)) & 0xFull) == 0xFull);
        }

        // pack x into half2 pairs (valid on even lanes)
        unsigned x16 = f2h(xin);
        unsigned xnb = (unsigned)__shfl_xor((int)x16, 1, 32);
        unsigned xpk = (xnb << 16) | x16;

        float ar = bcr, az = bcz, an = bcn;
        #pragma unroll
        for (int j = 0; j < NP; j++) {
            unsigned px = (unsigned)__shfl((int)xpk, 2*j, 32);
            ar = dot2(cr2[j], px, ar);
            az = dot2(cz2[j], px, az);
            an = dot2(cn2[j], px, an);
        }

        // pack h into half2 pairs
        unsigned h16 = f2h(h);
        unsigned hnb = (unsigned)__shfl_xor((int)h16, 1, 32);
        unsigned hpk = (hnb << 16) | h16;

        float hr = bhr, hz = bhz, hn = bhn;
        #pragma unroll
        for (int j = 0; j < 16; j++) {
            unsigned ph = (unsigned)__shfl((int)hpk, 2*j, 32);
            hr = dot2(whr[j], ph, hr);
            hz = dot2(whz[j], ph, hz);
            hn = dot2(whn[j], ph, hn);
        }

        float r = fast_rcp(1.f + __expf(-(ar + hr)));
        float z = fast_rcp(1.f + __expf(-(az + hz)));
        float pre = an + r*hn;
        float e2 = __expf(2.f*pre);
        float n = 1.f - 2.f*fast_rcp(e2 + 1.f);
        h = n + z*(h - n);

        // bf16 pair-dword store (no sub-dword stores)
        unsigned bf = f2bf(h);
        unsigned nb = (unsigned)__shfl_xor((int)bf, 1, 32);
        if ((lane & 1) == 0)
            *(unsigned*)(feat_out + t*32 + lane) = (nb << 16) | bf;

        if (DO_MASK && lane == 0) mask_out[t*2] = ok ? 1.f : 0.f;
    }
    *hT_out = h;
}

__global__ __launch_bounds__(256) void gru_kernel(
    const float* __restrict__ obs, const float* __restrict__ rnn,
    const float* __restrict__ ws,
    const float* __restrict__ air_bhh, const float* __restrict__ m_bhh,
    unsigned short* __restrict__ air_feat, unsigned short* __restrict__ m_feat,
    float* __restrict__ mask_f, float* __restrict__ nh_out, int r0)
{
    int lane = threadIdx.x & 31;
    int half = (threadIdx.x >> 5) & 1;
    int r = r0 + blockIdx.x*8 + (threadIdx.x >> 5);
    if (r < BB) {
        const float* in_base = obs + r*(TT*15) + 8;
        float h0 = rnn[r*96 + lane];
        gru_row<7,4,false>(in_base,
                         (const unsigned*)(ws + OFF_WC2A), ws + OFF_BCA,
                         (const unsigned*)(ws + OFF_WH2A), air_bhh, h0,
                         air_feat + (size_t)r*TT*32,
                         nh_out + r*96 + lane, nullptr, lane, half);
    } else {
        int i = r - BB;
        int b = (i < BB) ? i : i - BB;
        int slot = (i < BB) ? 0 : 1;
        const float* in_base = obs + b*(TT*15) + slot*4;
        float h0 = rnn[(i >> 1)*96 + 32 + (i & 1)*32 + lane];
        gru_row<4,2,true>(in_base,
                        (const unsigned*)(ws + OFF_WC2M), ws + OFF_BCM,
                        (const unsigned*)(ws + OFF_WH2M), m_bhh, h0,
                        m_feat + (size_t)i*TT*32,
                        nh_out + (i >> 1)*96 + 32 + (i & 1)*32 + lane,
                        mask_f + (size_t)(b*TT)*2 + slot, lane, half);
    }
}

// ---------------- fused attention + MLP (bf16 MFMA, ct-split, pipelined) ----
__global__ __launch_bounds__(256) void fused_kernel(
    const unsigned short* __restrict__ air_feat, const unsigned short* __restrict__ m_feat,
    const float* __restrict__ mask_f,
    const unsigned short* __restrict__ wqkv, const float* __restrict__ attn_in_b,
    const unsigned short* __restrict__ wop,  const float* __restrict__ attn_out_b,
    const unsigned short* __restrict__ w0p, const float* __restrict__ b0,
    const unsigned short* __restrict__ w1p, const float* __restrict__ b1,
    const float* __restrict__ outW, const float* __restrict__ outb,
    float* __restrict__ val)
{
    __shared__ unsigned short A1[64*72];   // fusion: air 0-31, attn 32-63 (persists)
    __shared__ unsigned short U[64*264];   // phase1: AM(64*72)+CT(64*40); phase2: A2
    __shared__ float MS[128];
    __shared__ float PS[4][64];

    unsigned short* AM = U;
    unsigned short* CT = U + 64*72;
    unsigned short* A2 = U;

    const int tid  = threadIdx.x;
    const int lane = tid & 63;
    const int strip = tid >> 6;
    const int col  = lane & 15;
    const int quad = lane >> 4;
    const size_t n0 = (size_t)blockIdx.x * 64;

    // ---- attn weight frags: load BEFORE barrier (fly during staging drain)
    short8 wqf[2], wkf[2], wvf[2], wof[2];
    #pragma unroll
    for (int ct = 0; ct < 2; ct++) {
        wqf[ct] = *(const short8*)(wqkv + ((0+ct)*64 + lane)*8);
        wkf[ct] = *(const short8*)(wqkv + ((2+ct)*64 + lane)*8);
        wvf[ct] = *(const short8*)(wqkv + ((4+ct)*64 + lane)*8);
        wof[ct] = *(const short8*)(wop + (ct*64 + lane)*8);
    }

    // ---- stage bf16 feats directly ----
    {
        int row = tid >> 2, c0 = (tid & 3)*8;
        short8 va  = *(const short8*)(air_feat + (n0 + row)*32 + c0);
        *(short8*)&A1[row*72 + c0] = va;
        short8 vm1 = *(const short8*)(m_feat + (n0 + row)*32 + c0);
        *(short8*)&AM[row*72 + c0] = vm1;
        short8 vm2 = *(const short8*)(m_feat + ((size_t)NN + n0 + row)*32 + c0);
        *(short8*)&AM[row*72 + 32 + c0] = vm2;
        if (tid < 128) MS[tid] = mask_f[n0*2 + tid];
    }
    __syncthreads();

    // ---- attention (per-strip) ----
    {
        short8 a_air = *(const short8*)&A1[(strip*16 + col)*72 + quad*8];
        short8 a_m1  = *(const short8*)&AM[(strip*16 + col)*72 + quad*8];
        short8 a_m2  = *(const short8*)&AM[(strip*16 + col)*72 + 32 + quad*8];

        f32x4 q[2], k1[2], k2[2], v1[2], v2[2], ao[2];
        #pragma unroll
        for (int ct = 0; ct < 2; ct++) {
            f32x4 z = (f32x4){0.f,0.f,0.f,0.f};
            q[ct]  = __builtin_amdgcn_mfma_f32_16x16x32_bf16(a_air, wqf[ct], z, 0,0,0);
            k1[ct] = __builtin_amdgcn_mfma_f32_16x16x32_bf16(a_m1,  wkf[ct], z, 0,0,0);
            k2[ct] = __builtin_amdgcn_mfma_f32_16x16x32_bf16(a_m2,  wkf[ct], z, 0,0,0);
            v1[ct] = __builtin_amdgcn_mfma_f32_16x16x32_bf16(a_m1,  wvf[ct], z, 0,0,0);
            v2[ct] = __builtin_amdgcn_mfma_f32_16x16x32_bf16(a_m2,  wvf[ct], z, 0,0,0);
        }
        float bqr[2], bkr[2], bvr[2];
        #pragma unroll
        for (int ct = 0; ct < 2; ct++) {
            bqr[ct] = attn_in_b[ct*16 + col];
            bkr[ct] = attn_in_b[32 + ct*16 + col];
            bvr[ct] = attn_in_b[64 + ct*16 + col];
        }
        float p1s[2][4], p2s[2][4];
        #pragma unroll
        for (int ct = 0; ct < 2; ct++) {
            #pragma unroll
            for (int reg = 0; reg < 4; reg++) {
                float qq = q[ct][reg] + bqr[ct];
                float p1 = qq * (k1[ct][reg] + bkr[ct]);
                float p2 = qq * (k2[ct][reg] + bkr[ct]);
                #pragma unroll
                for (int m = 1; m < 16; m <<= 1) {
                    p1 += __shfl_xor(p1, m, 64);
                    p2 += __shfl_xor(p2, m, 64);
                }
                p1s[ct][reg] = p1; p2s[ct][reg] = p2;
            }
        }
        float bothm[4];
        #pragma unroll
        for (int reg = 0; reg < 4; reg++) {
            int rloc = strip*16 + quad*4 + reg;
            float m0v = MS[rloc*2], m1v = MS[rloc*2 + 1];
            bothm[reg] = (m0v > 0.5f && m1v > 0.5f) ? 1.f : 0.f;
            #pragma unroll
            for (int ct = 0; ct < 2; ct++) {
                float s1 = p1s[ct][reg]*0.25f + (m0v > 0.5f ? -1e9f : 0.f);
                float s2 = p2s[ct][reg]*0.25f + (m1v > 0.5f ? -1e9f : 0.f);
                float mx = fmaxf(s1, s2);
                float e1 = __expf(s1 - mx), e2 = __expf(s2 - mx);
                float inv = fast_rcp(e1 + e2);
                float ctxv = ((v1[ct][reg] + bvr[ct])*e1 +
                              (v2[ct][reg] + bvr[ct])*e2) * inv;
                CT[rloc*40 + ct*16 + col] = f2bf(ctxv);
            }
        }
        short8 a_ctx = *(const short8*)&CT[(strip*16 + col)*40 + quad*8];
        #pragma unroll
        for (int ct = 0; ct < 2; ct++) {
            f32x4 z = (f32x4){0.f,0.f,0.f,0.f};
            ao[ct] = __builtin_amdgcn_mfma_f32_16x16x32_bf16(a_ctx, wof[ct], z, 0,0,0);
        }
        float bor[2] = { attn_out_b[col], attn_out_b[16 + col] };
        #pragma unroll
        for (int reg = 0; reg < 4; reg++) {
            int rloc = strip*16 + quad*4 + reg;
            #pragma unroll
            for (int ct = 0; ct < 2; ct++) {
                float av = ao[ct][reg] + bor[ct];
                av = (bothm[reg] > 0.5f) ? 0.f : av;
                A1[rloc*72 + 32 + ct*16 + col] = f2bf(av);
            }
        }
    }
    __syncthreads();   // attention done; A1 complete; AM/CT now dead

    // per-lane bias / out-weight for this wave's 4 col-tiles
    float b0r[4], b1r[4], owr[4];
    #pragma unroll
    for (int c = 0; c < 4; c++) {
        int ct = strip*4 + c;
        b0r[c] = b0[ct*16 + col];
        b1r[c] = b1[ct*16 + col];
        owr[c] = outW[ct*16 + col];
    }
    const float outb0 = outb[0];

    // ---- layer 1: all 64 rows x this wave's 4 ct, K=64 (pipelined B-frags) --
    f32x4 acc1[4][4];   // [row-strip s][ct-local]
    #pragma unroll
    for (int s = 0; s < 4; s++)
        #pragma unroll
        for (int c = 0; c < 4; c++) acc1[s][c] = (f32x4){0.f,0.f,0.f,0.f};
    {
        short8 bfr[4], nbfr[4];
        #pragma unroll
        for (int c = 0; c < 4; c++)
            bfr[c] = *(const short8*)(w0p + ((0*16 + strip*4 + c)*64 + lane)*8);
        #pragma unroll
        for (int ks = 0; ks < 2; ks++) {
            if (ks < 1) {
                #pragma unroll
                for (int c = 0; c < 4; c++)
                    nbfr[c] = *(const short8*)(w0p + (((ks+1)*16 + strip*4 + c)*64 + lane)*8);
            }
            short8 a[4];
            #pragma unroll
            for (int s = 0; s < 4; s++)
                a[s] = *(const short8*)&A1[(s*16 + col)*72 + ks*32 + quad*8];
            #pragma unroll
            for (int c = 0; c < 4; c++)
                #pragma unroll
                for (int s = 0; s < 4; s++)
                    acc1[s][c] = __builtin_amdgcn_mfma_f32_16x16x32_bf16(a[s], bfr[c], acc1[s][c], 0, 0, 0);
            #pragma unroll
            for (int c = 0; c < 4; c++) bfr[c] = nbfr[c];
        }
    }
    __syncthreads();   // everyone done reading A1/U-phase1 before A2 overwrite
    #pragma unroll
    for (int s = 0; s < 4; s++) {
        #pragma unroll
        for (int c = 0; c < 4; c++) {
            int ct = strip*4 + c;
            #pragma unroll
            for (int reg = 0; reg < 4; reg++) {
                float h = acc1[s][c][reg] + b0r[c];
                h = (h > 0.f) ? h : 0.01f*h;
                A2[(s*16 + quad*4 + reg)*264 + ct*16 + col] = f2bf(h);
            }
        }
    }
    __syncthreads();

    // ---- layer 2: all 64 rows x this wave's 4 ct, K=256 (pipelined) ----
    f32x4 acc2[4][4];
    #pragma unroll
    for (int s = 0; s < 4; s++)
        #pragma unroll
        for (int c = 0; c < 4; c++) acc2[s][c] = (f32x4){0.f,0.f,0.f,0.f};
    {
        short8 bfr[4], nbfr[4];
        #pragma unroll
        for (int c = 0; c < 4; c++)
            bfr[c] = *(const short8*)(w1p + ((0*16 + strip*4 + c)*64 + lane)*8);
        #pragma unroll
        for (int ks = 0; ks < 8; ks++) {
            if (ks < 7) {
                #pragma unroll
                for (int c = 0; c < 4; c++)
                    nbfr[c] = *(const short8*)(w1p + (((ks+1)*16 + strip*4 + c)*64 + lane)*8);
            }
            short8 a[4];
            #pragma unroll
            for (int s = 0; s < 4; s++)
                a[s] = *(const short8*)&A2[(s*16 + col)*264 + ks*32 + quad*8];
            #pragma unroll
            for (int c = 0; c < 4; c++)
                #pragma unroll
                for (int s = 0; s < 4; s++)
                    acc2[s][c] = __builtin_amdgcn_mfma_f32_16x16x32_bf16(a[s], bfr[c], acc2[s][c], 0, 0, 0);
            #pragma unroll
            for (int c = 0; c < 4; c++) bfr[c] = nbfr[c];
        }
    }

    // ---- out layer: partial dot per wave, reduce across col-lanes + waves ----
    #pragma unroll
    for (int s = 0; s < 4; s++) {
        float pv[4];
        #pragma unroll
        for (int reg = 0; reg < 4; reg++) pv[reg] = 0.f;
        #pragma unroll
        for (int c = 0; c < 4; c++) {
            #pragma unroll
            for (int reg = 0; reg < 4; reg++) {
                float h = acc2[s][c][reg] + b1r[c];
                h = (h > 0.f) ? h : 0.01f*h;
                pv[reg] += h*owr[c];
            }
        }
        #pragma unroll
        for (int reg = 0; reg < 4; reg++) {
            #pragma unroll
            for (int m = 1; m < 16; m <<= 1)
                pv[reg] += __shfl_xor(pv[reg], m, 64);
            if (col == 0) PS[strip][s*16 + quad*4 + reg] = pv[reg];
        }
    }
    __syncthreads();
    if (tid < 64)
        val[n0 + tid] = PS[0][tid] + PS[1][tid] + PS[2][tid] + PS[3][tid] + outb0;
}

// ---------------- launch ---------------------------------------------------
extern "C" void kernel_launch(void* const* d_in, const int* in_sizes, int n_in,
                              void* d_out, int out_size, void* d_ws, size_t ws_size,
                              hipStream_t stream) {
    const float* obs        = (const float*)d_in[0];
    const float* rnn        = (const float*)d_in[1];
    const float* enc_air_W  = (const float*)d_in[2];
    const float* enc_air_b  = (const float*)d_in[3];
    const float* enc_m_W    = (const float*)d_in[4];
    const float* enc_m_b    = (const float*)d_in[5];
    const float* air_Wih    = (const float*)d_in[6];
    const float* air_Whh    = (const float*)d_in[7];
    const float* air_bih    = (const float*)d_in[8];
    const float* air_bhh    = (const float*)d_in[9];
    const float* m_Wih      = (const float*)d_in[10];
    const float* m_Whh      = (const float*)d_in[11];
    const float* m_bih      = (const float*)d_in[12];
    const float* m_bhh      = (const float*)d_in[13];
    const float* attn_in_w  = (const float*)d_in[14];
    const float* attn_in_b  = (const float*)d_in[15];
    const float* attn_out_w = (const float*)d_in[16];
    const float* attn_out_b = (const float*)d_in[17];
    const float* mlp_W0     = (const float*)d_in[18];
    const float* mlp_b0     = (const float*)d_in[19];
    const float* mlp_W1     = (const float*)d_in[20];
    const float* mlp_b1     = (const float*)d_in[21];
    const float* out_W      = (const float*)d_in[22];
    const float* out_b      = (const float*)d_in[23];

    float* ws  = (float*)d_ws;
    float* out = (float*)d_out;

    prep_kernel<<<44, 256, 0, stream>>>(enc_air_W, enc_air_b, enc_m_W, enc_m_b,
                                        air_Wih, air_bih, m_Wih, m_bih,
                                        air_Whh, m_Whh,
                                        mlp_W0, mlp_W1, attn_in_w, attn_out_w, ws);

    // split into two dispatches (same total work) so fused shows in rocprof top-5
    gru_kernel<<<384, 256, 0, stream>>>(obs, rnn, ws, air_bhh, m_bhh,
                                        (unsigned short*)(ws + OFF_AIRF),
                                        (unsigned short*)(ws + OFF_MF),
                                        ws + OFF_MASK, out + NVAL, 0);
    gru_kernel<<<384, 256, 0, stream>>>(obs, rnn, ws, air_bhh, m_bhh,
                                        (unsigned short*)(ws + OFF_AIRF),
                                        (unsigned short*)(ws + OFF_MF),
                                        ws + OFF_MASK, out + NVAL, 3072);

    fused_kernel<<<NN/64, 256, 0, stream>>>((const unsigned short*)(ws + OFF_AIRF),
                                            (const unsigned short*)(ws + OFF_MF),
                                            ws + OFF_MASK,
                                            (const unsigned short*)(ws + OFF_WQKV), attn_in_b,
                                            (const unsigned short*)(ws + OFF_WO),   attn_out_b,
                                            (const unsigned short*)(ws + OFF_W0P), mlp_b0,
                                            (const unsigned short*)(ws + OFF_W1P), mlp_b1,
                                            out_W, out_b, out);
}

// Round 14
// 320.696 us; speedup vs baseline: 1.2053x; 1.2053x over previous
//
#include <hip/hip_runtime.h>
#include <hip/hip_bf16.h>

#define BB 2048
#define TT 128
#define NN (BB*TT)          // 262144
#define NVAL NN

// workspace layout (float offsets)
#define OFF_BCA   768u        // 96 combined air input bias
#define OFF_BCM   1632u       // 96 combined m input bias
#define OFF_W0P   2048u       // W0 B-frag pack (16384 bf16)
#define OFF_W1P   10240u      // W1 B-frag pack (65536 bf16)
#define OFF_WQKV  43008u      // attn_in_w B-frag pack
#define OFF_WO    44544u      // attn_out_w B-frag pack
#define OFF_WH2A  45568u      // air Whh fp16-pair pack: 96*16 uints
#define OFF_WH2M  47104u      // m Whh fp16-pair pack
#define OFF_WC2A  48640u      // air combined Wih fp16-pair pack: 96*4 uints
#define OFF_WC2M  49024u      // m combined Wih fp16-pair pack
#define OFF_AIRF  83968u      // air_feat bf16: NN*32 shorts = 4194304 floats
#define OFF_MF    4278272u    // m_feat bf16: 2*NN*32 shorts = 8388608 floats
#define OFF_MASK  12666880u   // N*2 mask floats

typedef __attribute__((ext_vector_type(8))) short short8;
typedef __attribute__((ext_vector_type(4))) float f32x4;
typedef _Float16 h2 __attribute__((ext_vector_type(2)));

__device__ __forceinline__ unsigned short f2bf(float f) {
    unsigned u = __builtin_bit_cast(unsigned, f);
    u += 0x7FFFu + ((u >> 16) & 1u);       // RNE
    return (unsigned short)(u >> 16);
}
__device__ __forceinline__ unsigned f2h(float f) {
    _Float16 h = (_Float16)f;
    return (unsigned)__builtin_bit_cast(unsigned short, h);
}
__device__ __forceinline__ unsigned pkh2(float a, float b) {
    return (f2h(b) << 16) | f2h(a);
}
__device__ __forceinline__ float dot2(unsigned w, unsigned x, float acc) {
    return __builtin_amdgcn_fdot2(__builtin_bit_cast(h2, w),
                                  __builtin_bit_cast(h2, x), acc, false);
}
__device__ __forceinline__ float fast_rcp(float x) {
    return __builtin_amdgcn_rcpf(x);
}

// ---------------- prep -----------------------------------------------------
__global__ __launch_bounds__(256) void prep_kernel(
    const float* __restrict__ enc_air_W, const float* __restrict__ enc_air_b,
    const float* __restrict__ enc_m_W,   const float* __restrict__ enc_m_b,
    const float* __restrict__ air_Wih,   const float* __restrict__ air_bih,
    const float* __restrict__ m_Wih,     const float* __restrict__ m_bih,
    const float* __restrict__ air_Whh,   const float* __restrict__ m_Whh,
    const float* __restrict__ W0,        const float* __restrict__ W1,
    const float* __restrict__ attn_in_w, const float* __restrict__ attn_out_w,
    float* __restrict__ ws)
{
    int b = blockIdx.x, t = threadIdx.x;
    if (b == 0) {
        if (t < 96) {
            float bacc = air_bih[t];
            for (int k = 0; k < 32; k++) bacc += air_Wih[t*32+k] * enc_air_b[k];
            ws[OFF_BCA + t] = bacc;
            float bacc2 = m_bih[t];
            for (int k = 0; k < 32; k++) bacc2 += m_Wih[t*32+k] * enc_m_b[k];
            ws[OFF_BCM + t] = bacc2;
        }
    } else if (b <= 32) {
        unsigned short* w1p = (unsigned short*)(ws + OFF_W1P);
        int base = ((b-1)*256 + t);
        int lane = base & 63;
        int ctf  = base >> 6;
        int ct   = ctf & 15, s = ctf >> 4;   // s 0..7
        int col = lane & 15, quad = lane >> 4;
        int k0 = s*32 + quad*8;
        int o  = ct*16 + col;
        #pragma unroll
        for (int j = 0; j < 8; j++)
            w1p[base*8 + j] = f2bf(W1[o*256 + k0 + j]);
    } else if (b <= 40) {
        unsigned short* w0p = (unsigned short*)(ws + OFF_W0P);
        int base = ((b-33)*256 + t);
        int lane = base & 63;
        int ctf  = base >> 6;
        int ct   = ctf & 15, s = ctf >> 4;   // s 0..1
        int col = lane & 15, quad = lane >> 4;
        int k0 = s*32 + quad*8;
        int o  = ct*16 + col;
        #pragma unroll
        for (int j = 0; j < 8; j++)
            w0p[base*8 + j] = f2bf(W0[o*64 + k0 + j]);
    } else if (b == 41) { // attention weight packs
        unsigned short* wqkv = (unsigned short*)(ws + OFF_WQKV);
        unsigned short* wop  = (unsigned short*)(ws + OFF_WO);
        for (int slot = t; slot < 512; slot += 256) {
            if (slot < 384) {
                int ct = slot >> 6, lane = slot & 63;
                int col = lane & 15, quad = lane >> 4;
                int o = ct*16 + col;
                #pragma unroll
                for (int j = 0; j < 8; j++)
                    wqkv[slot*8 + j] = f2bf(attn_in_w[o*32 + quad*8 + j]);
            } else {
                int s2 = slot - 384;
                int ct = s2 >> 6, lane = s2 & 63;
                int col = lane & 15, quad = lane >> 4;
                #pragma unroll
                for (int j = 0; j < 8; j++)
                    wop[s2*8 + j] = f2bf(attn_out_w[(ct*16+col)*32 + quad*8 + j]);
            }
        }
    } else if (b == 42) { // GRU Whh fp16-pair packs: [gate*32+o][16 pairs]
        unsigned* wa = (unsigned*)(ws + OFF_WH2A);
        unsigned* wm = (unsigned*)(ws + OFF_WH2M);
        for (int s = t; s < 3072; s += 256) {
            int s2 = (s < 1536) ? s : s - 1536;
            const float* W = (s < 1536) ? air_Whh : m_Whh;
            unsigned* dst = (s < 1536) ? wa : wm;
            int o = s2 >> 4, j = s2 & 15;
            dst[s2] = pkh2(W[o*32 + 2*j], W[o*32 + 2*j + 1]);
        }
    } else { // b == 43: combined input-weight fp16-pair packs: [gate*32+o][4 pairs]
        unsigned* wa = (unsigned*)(ws + OFF_WC2A);
        unsigned* wm = (unsigned*)(ws + OFF_WC2M);
        for (int s = t; s < 768; s += 256) {
            int s2 = (s < 384) ? s : s - 384;
            bool is_air = (s < 384);
            unsigned* dst = is_air ? wa : wm;
            int o = s2 >> 2, j = s2 & 3;
            int ni  = is_air ? 7 : 4;
            float c0 = 0.f, c1 = 0.f;
            int i0 = 2*j, i1 = 2*j + 1;
            if (i0 < ni)
                for (int k = 0; k < 32; k++)
                    c0 += (is_air ? air_Wih[o*32+k]*enc_air_W[k*7+i0]
                                  : m_Wih[o*32+k]*enc_m_W[k*4+i0]);
            if (i1 < ni)
                for (int k = 0; k < 32; k++)
                    c1 += (is_air ? air_Wih[o*32+k]*enc_air_W[k*7+i1]
                                  : m_Wih[o*32+k]*enc_m_W[k*4+i1]);
            dst[s2] = pkh2(c0, c1);
        }
    }
}

// ---------------- GRU (VALU + fp16 dot2, single row / 32-lane group) --------
// R10 structure + rcpf + dual accumulation chains in the h-loop (halves the
// per-gate dependent-dot2 depth: 16 -> 8, six independent chains).
template<int NI, int NP, bool DO_MASK>
__device__ void gru_row(const float* __restrict__ in_base,
                        const unsigned* __restrict__ wc2,   // [3*32][4]
                        const float* __restrict__ bc,
                        const unsigned* __restrict__ wh2,   // [3*32][16]
                        const float* __restrict__ bhh,
                        float h0,
                        unsigned short* __restrict__ feat_out,
                        float* __restrict__ hT_out,
                        float* __restrict__ mask_out,
                        int lane, int half)
{
    unsigned whr[16], whz[16], whn[16];
    #pragma unroll
    for (int j = 0; j < 16; j++) {
        whr[j] = wh2[lane*16 + j];
        whz[j] = wh2[(32+lane)*16 + j];
        whn[j] = wh2[(64+lane)*16 + j];
    }
    unsigned cr2[NP], cz2[NP], cn2[NP];
    #pragma unroll
    for (int j = 0; j < NP; j++) {
        cr2[j] = wc2[lane*4 + j];
        cz2[j] = wc2[(32+lane)*4 + j];
        cn2[j] = wc2[(64+lane)*4 + j];
    }
    const float bcr = bc[lane], bcz = bc[32+lane], bcn = bc[64+lane];
    const float bhr = bhh[lane], bhz = bhh[32+lane], bhn = bhh[64+lane];

    float h = h0;
    for (int t = 0; t < TT; t++) {
        float xin = (lane < NI) ? in_base[t*15 + lane] : 0.f;

        bool ok = true;
        if (DO_MASK) {
            bool pred = true;
            if (lane < 4) {
                const float c   = ((lane & 1) == 0) ? 1.f : 0.f;
                const float thr = ((lane & 1) == 0) ? 1.00001e-5f : 1e-8f;
                pred = fabsf(xin - c) <= thr;
            }
            unsigned long long ball = __ballot(pred);
            ok = (((ball >> (half*32)) & 0xFull) == 0xFull);
        }

        // pack x into half2 pairs (valid on even lanes)
        unsigned x16 = f2h(xin);
        unsigned xnb = (unsigned)__shfl_xor((int)x16, 1, 32);
        unsigned xpk = (xnb << 16) | x16;

        float ar = bcr, az = bcz, an = bcn;
        #pragma unroll
        for (int j = 0; j < NP; j++) {
            unsigned px = (unsigned)__shfl((int)xpk, 2*j, 32);
            ar = dot2(cr2[j], px, ar);
            az = dot2(cz2[j], px, az);
            an = dot2(cn2[j], px, an);
        }

        // pack h into half2 pairs
        unsigned h16 = f2h(h);
        unsigned hnb = (unsigned)__shfl_xor((int)h16, 1, 32);
        unsigned hpk = (hnb << 16) | h16;

        // dual accumulation chains per gate (j 0-7 and 8-15 independent)
        float hr0 = bhr, hz0 = bhz, hn0 = bhn;
        float hr1 = 0.f, hz1 = 0.f, hn1 = 0.f;
        #pragma unroll
        for (int j = 0; j < 8; j++) {
            unsigned pa = (unsigned)__shfl((int)hpk, 2*j, 32);
            unsigned pb = (unsigned)__shfl((int)hpk, 2*(j+8), 32);
            hr0 = dot2(whr[j],   pa, hr0);
            hr1 = dot2(whr[j+8], pb, hr1);
            hz0 = dot2(whz[j],   pa, hz0);
            hz1 = dot2(whz[j+8], pb, hz1);
            hn0 = dot2(whn[j],   pa, hn0);
            hn1 = dot2(whn[j+8], pb, hn1);
        }
        float hr = hr0 + hr1, hz = hz0 + hz1, hn = hn0 + hn1;

        float r = fast_rcp(1.f + __expf(-(ar + hr)));
        float z = fast_rcp(1.f + __expf(-(az + hz)));
        float pre = an + r*hn;
        float e2 = __expf(2.f*pre);
        float n = 1.f - 2.f*fast_rcp(e2 + 1.f);
        h = n + z*(h - n);

        // bf16 pair-dword store (no sub-dword stores)
        unsigned bf = f2bf(h);
        unsigned nb = (unsigned)__shfl_xor((int)bf, 1, 32);
        if ((lane & 1) == 0)
            *(unsigned*)(feat_out + t*32 + lane) = (nb << 16) | bf;

        if (DO_MASK && lane == 0) mask_out[t*2] = ok ? 1.f : 0.f;
    }
    *hT_out = h;
}

__global__ __launch_bounds__(256) void gru_kernel(
    const float* __restrict__ obs, const float* __restrict__ rnn,
    const float* __restrict__ ws,
    const float* __restrict__ air_bhh, const float* __restrict__ m_bhh,
    unsigned short* __restrict__ air_feat, unsigned short* __restrict__ m_feat,
    float* __restrict__ mask_f, float* __restrict__ nh_out)
{
    int lane = threadIdx.x & 31;
    int half = (threadIdx.x >> 5) & 1;
    int r = blockIdx.x*8 + (threadIdx.x >> 5);
    if (r < BB) {
        const float* in_base = obs + r*(TT*15) + 8;
        float h0 = rnn[r*96 + lane];
        gru_row<7,4,false>(in_base,
                         (const unsigned*)(ws + OFF_WC2A), ws + OFF_BCA,
                         (const unsigned*)(ws + OFF_WH2A), air_bhh, h0,
                         air_feat + (size_t)r*TT*32,
                         nh_out + r*96 + lane, nullptr, lane, half);
    } else {
        int i = r - BB;
        int b = (i < BB) ? i : i - BB;
        int slot = (i < BB) ? 0 : 1;
        const float* in_base = obs + b*(TT*15) + slot*4;
        float h0 = rnn[(i >> 1)*96 + 32 + (i & 1)*32 + lane];
        gru_row<4,2,true>(in_base,
                        (const unsigned*)(ws + OFF_WC2M), ws + OFF_BCM,
                        (const unsigned*)(ws + OFF_WH2M), m_bhh, h0,
                        m_feat + (size_t)i*TT*32,
                        nh_out + (i >> 1)*96 + 32 + (i & 1)*32 + lane,
                        mask_f + (size_t)(b*TT)*2 + slot, lane, half);
    }
}

// ---------------- fused attention + MLP (bf16 MFMA, ct-split, pipelined) ----
__global__ __launch_bounds__(256) void fused_kernel(
    const unsigned short* __restrict__ air_feat, const unsigned short* __restrict__ m_feat,
    const float* __restrict__ mask_f,
    const unsigned short* __restrict__ wqkv, const float* __restrict__ attn_in_b,
    const unsigned short* __restrict__ wop,  const float* __restrict__ attn_out_b,
    const unsigned short* __restrict__ w0p, const float* __restrict__ b0,
    const unsigned short* __restrict__ w1p, const float* __restrict__ b1,
    const float* __restrict__ outW, const float* __restrict__ outb,
    float* __restrict__ val)
{
    __shared__ unsigned short A1[64*72];   // fusion: air 0-31, attn 32-63 (persists)
    __shared__ unsigned short U[64*264];   // phase1: AM(64*72)+CT(64*40); phase2: A2
    __shared__ float MS[128];
    __shared__ float PS[4][64];

    unsigned short* AM = U;
    unsigned short* CT = U + 64*72;
    unsigned short* A2 = U;

    const int tid  = threadIdx.x;
    const int lane = tid & 63;
    const int strip = tid >> 6;
    const int col  = lane & 15;
    const int quad = lane >> 4;
    const size_t n0 = (size_t)blockIdx.x * 64;

    // ---- attn weight frags: load BEFORE barrier (fly during staging drain)
    short8 wqf[2], wkf[2], wvf[2], wof[2];
    #pragma unroll
    for (int ct = 0; ct < 2; ct++) {
        wqf[ct] = *(const short8*)(wqkv + ((0+ct)*64 + lane)*8);
        wkf[ct] = *(const short8*)(wqkv + ((2+ct)*64 + lane)*8);
        wvf[ct] = *(const short8*)(wqkv + ((4+ct)*64 + lane)*8);
        wof[ct] = *(const short8*)(wop + (ct*64 + lane)*8);
    }

    // ---- stage bf16 feats directly ----
    {
        int row = tid >> 2, c0 = (tid & 3)*8;
        short8 va  = *(const short8*)(air_feat + (n0 + row)*32 + c0);
        *(short8*)&A1[row*72 + c0] = va;
        short8 vm1 = *(const short8*)(m_feat + (n0 + row)*32 + c0);
        *(short8*)&AM[row*72 + c0] = vm1;
        short8 vm2 = *(const short8*)(m_feat + ((size_t)NN + n0 + row)*32 + c0);
        *(short8*)&AM[row*72 + 32 + c0] = vm2;
        if (tid < 128) MS[tid] = mask_f[n0*2 + tid];
    }
    __syncthreads();

    // ---- attention (per-strip) ----
    {
        short8 a_air = *(const short8*)&A1[(strip*16 + col)*72 + quad*8];
        short8 a_m1  = *(const short8*)&AM[(strip*16 + col)*72 + quad*8];
        short8 a_m2  = *(const short8*)&AM[(strip*16 + col)*72 + 32 + quad*8];

        f32x4 q[2], k1[2], k2[2], v1[2], v2[2], ao[2];
        #pragma unroll
        for (int ct = 0; ct < 2; ct++) {
            f32x4 z = (f32x4){0.f,0.f,0.f,0.f};
            q[ct]  = __builtin_amdgcn_mfma_f32_16x16x32_bf16(a_air, wqf[ct], z, 0,0,0);
            k1[ct] = __builtin_amdgcn_mfma_f32_16x16x32_bf16(a_m1,  wkf[ct], z, 0,0,0);
            k2[ct] = __builtin_amdgcn_mfma_f32_16x16x32_bf16(a_m2,  wkf[ct], z, 0,0,0);
            v1[ct] = __builtin_amdgcn_mfma_f32_16x16x32_bf16(a_m1,  wvf[ct], z, 0,0,0);
            v2[ct] = __builtin_amdgcn_mfma_f32_16x16x32_bf16(a_m2,  wvf[ct], z, 0,0,0);
        }
        float bqr[2], bkr[2], bvr[2];
        #pragma unroll
        for (int ct = 0; ct < 2; ct++) {
            bqr[ct] = attn_in_b[ct*16 + col];
            bkr[ct] = attn_in_b[32 + ct*16 + col];
            bvr[ct] = attn_in_b[64 + ct*16 + col];
        }
        float p1s[2][4], p2s[2][4];
        #pragma unroll
        for (int ct = 0; ct < 2; ct++) {
            #pragma unroll
            for (int reg = 0; reg < 4; reg++) {
                float qq = q[ct][reg] + bqr[ct];
                float p1 = qq * (k1[ct][reg] + bkr[ct]);
                float p2 = qq * (k2[ct][reg] + bkr[ct]);
                #pragma unroll
                for (int m = 1; m < 16; m <<= 1) {
                    p1 += __shfl_xor(p1, m, 64);
                    p2 += __shfl_xor(p2, m, 64);
                }
                p1s[ct][reg] = p1; p2s[ct][reg] = p2;
            }
        }
        float bothm[4];
        #pragma unroll
        for (int reg = 0; reg < 4; reg++) {
            int rloc = strip*16 + quad*4 + reg;
            float m0v = MS[rloc*2], m1v = MS[rloc*2 + 1];
            bothm[reg] = (m0v > 0.5f && m1v > 0.5f) ? 1.f : 0.f;
            #pragma unroll
            for (int ct = 0; ct < 2; ct++) {
                float s1 = p1s[ct][reg]*0.25f + (m0v > 0.5f ? -1e9f : 0.f);
                float s2 = p2s[ct][reg]*0.25f + (m1v > 0.5f ? -1e9f : 0.f);
                float mx = fmaxf(s1, s2);
                float e1 = __expf(s1 - mx), e2 = __expf(s2 - mx);
                float inv = fast_rcp(e1 + e2);
                float ctxv = ((v1[ct][reg] + bvr[ct])*e1 +
                              (v2[ct][reg] + bvr[ct])*e2) * inv;
                CT[rloc*40 + ct*16 + col] = f2bf(ctxv);
            }
        }
        short8 a_ctx = *(const short8*)&CT[(strip*16 + col)*40 + quad*8];
        #pragma unroll
        for (int ct = 0; ct < 2; ct++) {
            f32x4 z = (f32x4){0.f,0.f,0.f,0.f};
            ao[ct] = __builtin_amdgcn_mfma_f32_16x16x32_bf16(a_ctx, wof[ct], z, 0,0,0);
        }
        float bor[2] = { attn_out_b[col], attn_out_b[16 + col] };
        #pragma unroll
        for (int reg = 0; reg < 4; reg++) {
            int rloc = strip*16 + quad*4 + reg;
            #pragma unroll
            for (int ct = 0; ct < 2; ct++) {
                float av = ao[ct][reg] + bor[ct];
                av = (bothm[reg] > 0.5f) ? 0.f : av;
                A1[rloc*72 + 32 + ct*16 + col] = f2bf(av);
            }
        }
    }
    __syncthreads();   // attention done; A1 complete; AM/CT now dead

    // per-lane bias / out-weight for this wave's 4 col-tiles
    float b0r[4], b1r[4], owr[4];
    #pragma unroll
    for (int c = 0; c < 4; c++) {
        int ct = strip*4 + c;
        b0r[c] = b0[ct*16 + col];
        b1r[c] = b1[ct*16 + col];
        owr[c] = outW[ct*16 + col];
    }
    const float outb0 = outb[0];

    // ---- layer 1: all 64 rows x this wave's 4 ct, K=64 (pipelined B-frags) --
    f32x4 acc1[4][4];   // [row-strip s][ct-local]
    #pragma unroll
    for (int s = 0; s < 4; s++)
        #pragma unroll
        for (int c = 0; c < 4; c++) acc1[s][c] = (f32x4){0.f,0.f,0.f,0.f};
    {
        short8 bfr[4], nbfr[4];
        #pragma unroll
        for (int c = 0; c < 4; c++)
            bfr[c] = *(const short8*)(w0p + ((0*16 + strip*4 + c)*64 + lane)*8);
        #pragma unroll
        for (int ks = 0; ks < 2; ks++) {
            if (ks < 1) {
                #pragma unroll
                for (int c = 0; c < 4; c++)
                    nbfr[c] = *(const short8*)(w0p + (((ks+1)*16 + strip*4 + c)*64 + lane)*8);
            }
            short8 a[4];
            #pragma unroll
            for (int s = 0; s < 4; s++)
                a[s] = *(const short8*)&A1[(s*16 + col)*72 + ks*32 + quad*8];
            #pragma unroll
            for (int c = 0; c < 4; c++)
                #pragma unroll
                for (int s = 0; s < 4; s++)
                    acc1[s][c] = __builtin_amdgcn_mfma_f32_16x16x32_bf16(a[s], bfr[c], acc1[s][c], 0, 0, 0);
            #pragma unroll
            for (int c = 0; c < 4; c++) bfr[c] = nbfr[c];
        }
    }
    __syncthreads();   // everyone done reading A1/U-phase1 before A2 overwrite
    #pragma unroll
    for (int s = 0; s < 4; s++) {
        #pragma unroll
        for (int c = 0; c < 4; c++) {
            int ct = strip*4 + c;
            #pragma unroll
            for (int reg = 0; reg < 4; reg++) {
                float h = acc1[s][c][reg] + b0r[c];
                h = (h > 0.f) ? h : 0.01f*h;
                A2[(s*16 + quad*4 + reg)*264 + ct*16 + col] = f2bf(h);
            }
        }
    }
    __syncthreads();

    // ---- layer 2: all 64 rows x this wave's 4 ct, K=256 (pipelined) ----
    f32x4 acc2[4][4];
    #pragma unroll
    for (int s = 0; s < 4; s++)
        #pragma unroll
        for (int c = 0; c < 4; c++) acc2[s][c] = (f32x4){0.f,0.f,0.f,0.f};
    {
        short8 bfr[4], nbfr[4];
        #pragma unroll
        for (int c = 0; c < 4; c++)
            bfr[c] = *(const short8*)(w1p + ((0*16 + strip*4 + c)*64 + lane)*8);
        #pragma unroll
        for (int ks = 0; ks < 8; ks++) {
            if (ks < 7) {
                #pragma unroll
                for (int c = 0; c < 4; c++)
                    nbfr[c] = *(const short8*)(w1p + (((ks+1)*16 + strip*4 + c)*64 + lane)*8);
            }
            short8 a[4];
            #pragma unroll
            for (int s = 0; s < 4; s++)
                a[s] = *(const short8*)&A2[(s*16 + col)*264 + ks*32 + quad*8];
            #pragma unroll
            for (int c = 0; c < 4; c++)
                #pragma unroll
                for (int s = 0; s < 4; s++)
                    acc2[s][c] = __builtin_amdgcn_mfma_f32_16x16x32_bf16(a[s], bfr[c], acc2[s][c], 0, 0, 0);
            #pragma unroll
            for (int c = 0; c < 4; c++) bfr[c] = nbfr[c];
        }
    }

    // ---- out layer: partial dot per wave, reduce across col-lanes + waves ----
    #pragma unroll
    for (int s = 0; s < 4; s++) {
        float pv[4];
        #pragma unroll
        for (int reg = 0; reg < 4; reg++) pv[reg] = 0.f;
        #pragma unroll
        for (int c = 0; c < 4; c++) {
            #pragma unroll
            for (int reg = 0; reg < 4; reg++) {
                float h = acc2[s][c][reg] + b1r[c];
                h = (h > 0.f) ? h : 0.01f*h;
                pv[reg] += h*owr[c];
            }
        }
        #pragma unroll
        for (int reg = 0; reg < 4; reg++) {
            #pragma unroll
            for (int m = 1; m < 16; m <<= 1)
                pv[reg] += __shfl_xor(pv[reg], m, 64);
            if (col == 0) PS[strip][s*16 + quad*4 + reg] = pv[reg];
        }
    }
    __syncthreads();
    if (tid < 64)
        val[n0 + tid] = PS[0][tid] + PS[1][tid] + PS[2][tid] + PS[3][tid] + outb0;
}

// ---------------- launch ---------------------------------------------------
extern "C" void kernel_launch(void* const* d_in, const int* in_sizes, int n_in,
                              void* d_out, int out_size, void* d_ws, size_t ws_size,
                              hipStream_t stream) {
    const float* obs        = (const float*)d_in[0];
    const float* rnn        = (const float*)d_in[1];
    const float* enc_air_W  = (const float*)d_in[2];
    const float* enc_air_b  = (const float*)d_in[3];
    const float* enc_m_W    = (const float*)d_in[4];
    const float* enc_m_b    = (const float*)d_in[5];
    const float* air_Wih    = (const float*)d_in[6];
    const float* air_Whh    = (const float*)d_in[7];
    const float* air_bih    = (const float*)d_in[8];
    const float* air_bhh    = (const float*)d_in[9];
    const float* m_Wih      = (const float*)d_in[10];
    const float* m_Whh      = (const float*)d_in[11];
    const float* m_bih      = (const float*)d_in[12];
    const float* m_bhh      = (const float*)d_in[13];
    const float* attn_in_w  = (const float*)d_in[14];
    const float* attn_in_b  = (const float*)d_in[15];
    const float* attn_out_w = (const float*)d_in[16];
    const float* attn_out_b = (const float*)d_in[17];
    const float* mlp_W0     = (const float*)d_in[18];
    const float* mlp_b0     = (const float*)d_in[19];
    const float* mlp_W1     = (const float*)d_in[20];
    const float* mlp_b1     = (const float*)d_in[21];
    const float* out_W      = (const float*)d_in[22];
    const float* out_b      = (const float*)d_in[23];

    float* ws  = (float*)d_ws;
    float* out = (float*)d_out;

    prep_kernel<<<44, 256, 0, stream>>>(enc_air_W, enc_air_b, enc_m_W, enc_m_b,
                                        air_Wih, air_bih, m_Wih, m_bih,
                                        air_Whh, m_Whh,
                                        mlp_W0, mlp_W1, attn_in_w, attn_out_w, ws);

    gru_kernel<<<768, 256, 0, stream>>>(obs, rnn, ws, air_bhh, m_bhh,
                                        (unsigned short*)(ws + OFF_AIRF),
                                        (unsigned short*)(ws + OFF_MF),
                                        ws + OFF_MASK, out + NVAL);

    fused_kernel<<<NN/64, 256, 0, stream>>>((const unsigned short*)(ws + OFF_AIRF),
                                            (const unsigned short*)(ws + OFF_MF),
                                            ws + OFF_MASK,
                                            (const unsigned short*)(ws + OFF_WQKV), attn_in_b,
                                            (const unsigned short*)(ws + OFF_WO),   attn_out_b,
                                            (const unsigned short*)(ws + OFF_W0P), mlp_b0,
                                            (const unsigned short*)(ws + OFF_W1P), mlp_b1,
                                            out_W, out_b, out);
}